// Round 2
// baseline (1450.945 us; speedup 1.0000x reference)
//
#include <hip/hip_runtime.h>

#define T_TOKENS 4096   // B*S
#define DIM      1024   // D
#define NEXP     8      // E
#define FDIM     4096   // F
#define NASSIGN  8192   // T_TOKENS * K
#define PADROWS  8320   // NASSIGN + 128 tile padding

typedef __bf16 bf16x8 __attribute__((ext_vector_type(8)));
typedef float  f32x4  __attribute__((ext_vector_type(4)));

__device__ __forceinline__ unsigned short f2b(float f) {
  unsigned u = __builtin_bit_cast(unsigned, f);
  u = u + 0x7fffu + ((u >> 16) & 1u);   // RNE, finite inputs only
  return (unsigned short)(u >> 16);
}
__device__ __forceinline__ float b2f(unsigned short h) {
  unsigned u = ((unsigned)h) << 16;
  return __builtin_bit_cast(float, u);
}
__device__ __forceinline__ void gload_lds16(const void* g, void* l) {
  __builtin_amdgcn_global_load_lds(
      (const __attribute__((address_space(1))) void*)g,
      (__attribute__((address_space(3))) void*)l, 16, 0, 0);
}

// ---------------- router: logits -> softmax -> top2 -> weights ----------------
__global__ void router_kernel(const float* __restrict__ x, const float* __restrict__ rw,
                              const float* __restrict__ rb, int* __restrict__ tidx,
                              float* __restrict__ tw, int* __restrict__ counts) {
  int gid = blockIdx.x * blockDim.x + threadIdx.x;
  int t = gid >> 6;
  int lane = threadIdx.x & 63;
  if (t >= T_TOKENS) return;
  const float* xr = x + (size_t)t * DIM;
  float acc[NEXP];
#pragma unroll
  for (int e = 0; e < NEXP; ++e) acc[e] = 0.f;
  for (int d = lane; d < DIM; d += 64) {
    float xv = xr[d];
    const float* r = rw + (size_t)d * NEXP;
#pragma unroll
    for (int e = 0; e < NEXP; ++e) acc[e] += xv * r[e];
  }
#pragma unroll
  for (int e = 0; e < NEXP; ++e) {
#pragma unroll
    for (int off = 32; off > 0; off >>= 1) acc[e] += __shfl_xor(acc[e], off);
  }
  if (lane == 0) {
    float lg[NEXP], m = -1e30f;
#pragma unroll
    for (int e = 0; e < NEXP; ++e) { lg[e] = acc[e] + rb[e]; m = fmaxf(m, lg[e]); }
    float p[NEXP], Z = 0.f;
#pragma unroll
    for (int e = 0; e < NEXP; ++e) { p[e] = expf(lg[e] - m); Z += p[e]; }
    int i0 = 0;
#pragma unroll
    for (int e = 1; e < NEXP; ++e) if (p[e] > p[i0]) i0 = e;
    int i1 = (i0 == 0) ? 1 : 0;
#pragma unroll
    for (int e = 0; e < NEXP; ++e) if (e != i0 && p[e] > p[i1]) i1 = e;
    float q0 = p[i0] / Z, q1 = p[i1] / Z;
    float s = q0 + q1 + 1e-8f;
    tidx[t * 2] = i0; tidx[t * 2 + 1] = i1;
    tw[t * 2] = q0 / s; tw[t * 2 + 1] = q1 / s;
    atomicAdd(&counts[i0], 1); atomicAdd(&counts[i1], 1);
  }
}

// ---------------- tiny scan: counts -> offsets, init cursors ----------------
__global__ void scan_kernel(const int* __restrict__ counts, int* __restrict__ offsets,
                            int* __restrict__ cursors) {
  if (threadIdx.x == 0) {
    int s = 0;
    for (int e = 0; e < NEXP; ++e) { offsets[e] = s; cursors[e] = s; s += counts[e]; }
    offsets[NEXP] = s;
  }
}

// ---------------- gather x rows (fp32 -> bf16) into expert-segmented Xg ----------------
__global__ void gather_kernel(const float* __restrict__ x, const int* __restrict__ tidx,
                              int* __restrict__ cursors, int* __restrict__ tslot,
                              unsigned short* __restrict__ Xg) {
  int aid = (blockIdx.x * blockDim.x + threadIdx.x) >> 6;
  int lane = threadIdx.x & 63;
  if (aid >= NASSIGN) return;
  int t = aid >> 1, k = aid & 1;
  int e = tidx[t * 2 + k];
  int slot = 0;
  if (lane == 0) {
    slot = atomicAdd(&cursors[e], 1);
    tslot[t * 2 + k] = slot;
  }
  slot = __shfl(slot, 0);
  const float4* xr = (const float4*)(x + (size_t)t * DIM);
  ushort4* dst = (ushort4*)(Xg + (size_t)slot * DIM);
#pragma unroll
  for (int i = 0; i < 4; ++i) {
    int idx = i * 64 + lane;
    float4 v = xr[idx];
    ushort4 o;
    o.x = f2b(v.x); o.y = f2b(v.y); o.z = f2b(v.z); o.w = f2b(v.w);
    dst[idx] = o;
  }
}

// ---------------- transpose + convert: src [E][R][C] f32 -> dst [E][C][R] bf16 ----------------
__global__ void transpose_cvt(const float* __restrict__ src, unsigned short* __restrict__ dst,
                              int R, int C) {
  __shared__ unsigned short tile[64][72];
  int e = blockIdx.z;
  const float* s = src + (size_t)e * R * C;
  unsigned short* d = dst + (size_t)e * R * C;
  int c0 = blockIdx.x * 64, r0 = blockIdx.y * 64;
  int tx = threadIdx.x & 15, ty = threadIdx.x >> 4;
#pragma unroll
  for (int i = 0; i < 4; ++i) {
    int r = i * 16 + ty;
    float4 v = *(const float4*)(s + (size_t)(r0 + r) * C + c0 + tx * 4);
    tile[r][tx * 4 + 0] = f2b(v.x);
    tile[r][tx * 4 + 1] = f2b(v.y);
    tile[r][tx * 4 + 2] = f2b(v.z);
    tile[r][tx * 4 + 3] = f2b(v.w);
  }
  __syncthreads();
#pragma unroll
  for (int i = 0; i < 4; ++i) {
    int c = i * 16 + ty;
    ushort4 o;
    o.x = tile[tx * 4 + 0][c];
    o.y = tile[tx * 4 + 1][c];
    o.z = tile[tx * 4 + 2][c];
    o.w = tile[tx * 4 + 3][c];
    *(ushort4*)(d + (size_t)(c0 + c) * R + r0 + tx * 4) = o;
  }
}

// ---------------- per-expert GEMM, 2-phase double-buffered (T3 minimum recipe) ----------------
// A: [slots][K] bf16 (expert segment rows), B: [E][N][K] bf16, Out: [slots][N] bf16
template <bool GELU, int K>
__global__ __launch_bounds__(256) void ffn_gemm(
    const unsigned short* __restrict__ A, const unsigned short* __restrict__ Bw,
    const float* __restrict__ bias, unsigned short* __restrict__ Out,
    const int* __restrict__ offsets, int N) {
  int e = blockIdx.z;
  int off = offsets[e];
  int n_e = offsets[e + 1] - off;
  int mt = blockIdx.x;
  if (mt * 128 >= n_e) return;
  int row0 = off + mt * 128;
  int rows_valid = n_e - mt * 128;
  if (rows_valid > 128) rows_valid = 128;
  int n0 = blockIdx.y * 128;

  __shared__ unsigned short As[2][128 * 64];
  __shared__ unsigned short Bs[2][128 * 64];

  int tid = threadIdx.x, w = tid >> 6, l = tid & 63;
  int wm = w >> 1, wn = w & 1;

  f32x4 acc[4][4] = {};

  const unsigned short* Ab = A + (size_t)row0 * K;
  const unsigned short* Bb = Bw + (size_t)e * N * K + (size_t)n0 * K;
  int sr = l >> 3;          // row within 8-row group
  int sc = (l & 7) * 8;     // bf16 elems (16B chunk)

  // stage K-subtile k0 into buffer `buf` (buf is a literal at every call site)
  auto stage = [&](int buf, int k0) {
#pragma unroll
    for (int i = 0; i < 4; ++i) {
      int r = w * 32 + i * 8;
      gload_lds16(Ab + (size_t)(r + sr) * K + k0 + sc, &As[buf][r * 64]);
      gload_lds16(Bb + (size_t)(r + sr) * K + k0 + sc, &Bs[buf][r * 64]);
    }
  };
  auto compute = [&](int buf) {
#pragma unroll
    for (int kk = 0; kk < 2; ++kk) {
      bf16x8 af[4], bfr[4];
#pragma unroll
      for (int i = 0; i < 4; ++i) {
        af[i]  = *(const bf16x8*)&As[buf][(wm * 64 + i * 16 + (l & 15)) * 64 + kk * 32 + (l >> 4) * 8];
        bfr[i] = *(const bf16x8*)&Bs[buf][(wn * 64 + i * 16 + (l & 15)) * 64 + kk * 32 + (l >> 4) * 8];
      }
#pragma unroll
      for (int i = 0; i < 4; ++i)
#pragma unroll
        for (int j = 0; j < 4; ++j)
          acc[i][j] = __builtin_amdgcn_mfma_f32_16x16x32_bf16(af[i], bfr[j], acc[i][j], 0, 0, 0);
    }
  };

  // prologue: fill buffer 0
  stage(0, 0);
  __syncthreads();           // drains vmcnt(0)

  // main loop: prefetch next subtile BEFORE computing current; one barrier per K-step.
  // Compile-time buffer indices (0/1) via 2-step unroll.
#pragma unroll 1
  for (int k0 = 0; k0 < K; k0 += 128) {
    if (k0 + 64 < K) stage(1, k0 + 64);
    compute(0);
    __syncthreads();
    if (k0 + 128 < K) stage(0, k0 + 128);
    compute(1);
    __syncthreads();
  }

  int cr = (l >> 4) * 4, cc = l & 15;
#pragma unroll
  for (int i = 0; i < 4; ++i) {
#pragma unroll
    for (int r = 0; r < 4; ++r) {
      int rl = wm * 64 + i * 16 + cr + r;
      if (rl < rows_valid) {
        size_t rowbase = (size_t)(row0 + rl) * N;
#pragma unroll
        for (int j = 0; j < 4; ++j) {
          int col = n0 + wn * 64 + j * 16 + cc;
          float v = acc[i][j][r] + bias[(size_t)e * N + col];
          if (GELU) v = 0.5f * v * (1.0f + erff(v * 0.70710678118654752f));
          Out[rowbase + col] = f2b(v);
        }
      }
    }
  }
}

// ---------------- combine: out = x + w0*EO[slot0] + w1*EO[slot1] ----------------
__global__ void combine_kernel(const float* __restrict__ x, const unsigned short* __restrict__ EO,
                               const int* __restrict__ tslot, const float* __restrict__ tw,
                               float* __restrict__ out) {
  int t = blockIdx.x;
  int s0 = tslot[t * 2], s1 = tslot[t * 2 + 1];
  float w0 = tw[t * 2], w1 = tw[t * 2 + 1];
  int i = threadIdx.x;  // float4 index, 256 * 4 = 1024 elems
  float4 xv = ((const float4*)(x + (size_t)t * DIM))[i];
  ushort4 a = ((const ushort4*)(EO + (size_t)s0 * DIM))[i];
  ushort4 b = ((const ushort4*)(EO + (size_t)s1 * DIM))[i];
  float4 o;
  o.x = xv.x + w0 * b2f(a.x) + w1 * b2f(b.x);
  o.y = xv.y + w0 * b2f(a.y) + w1 * b2f(b.y);
  o.z = xv.z + w0 * b2f(a.z) + w1 * b2f(b.z);
  o.w = xv.w + w0 * b2f(a.w) + w1 * b2f(b.w);
  ((float4*)(out + (size_t)t * DIM))[i] = o;
}

extern "C" void kernel_launch(void* const* d_in, const int* in_sizes, int n_in,
                              void* d_out, int out_size, void* d_ws, size_t ws_size,
                              hipStream_t stream) {
  const float* x        = (const float*)d_in[0];
  const float* router_w = (const float*)d_in[1];
  const float* router_b = (const float*)d_in[2];
  const float* w1       = (const float*)d_in[3];
  const float* b1       = (const float*)d_in[4];
  const float* w2       = (const float*)d_in[5];
  const float* b2       = (const float*)d_in[6];
  float* out = (float*)d_out;
  char* ws = (char*)d_ws;

  // workspace layout (bytes)
  int*   counts  = (int*)(ws + 0);
  int*   cursors = (int*)(ws + 64);
  int*   offsets = (int*)(ws + 128);
  int*   tidx    = (int*)(ws + 256);
  float* tw      = (float*)(ws + 256 + 32768);
  int*   tslot   = (int*)(ws + 256 + 65536);
  const size_t XG_OFF  = 1u << 20;
  const size_t XG_B    = (size_t)PADROWS * DIM * 2;        // 17,039,360
  const size_t H_OFF   = XG_OFF + XG_B;
  const size_t H_B     = (size_t)PADROWS * FDIM * 2;       // 68,157,440
  const size_t EO_OFF  = H_OFF + H_B;
  const size_t EO_B    = XG_B;
  const size_t W1T_OFF = EO_OFF + EO_B;
  const size_t WT_B    = (size_t)NEXP * DIM * FDIM * 2;    // 67,108,864
  const size_t W2T_OFF = W1T_OFF + WT_B;
  unsigned short* Xg  = (unsigned short*)(ws + XG_OFF);
  unsigned short* H   = (unsigned short*)(ws + H_OFF);
  unsigned short* EO  = (unsigned short*)(ws + EO_OFF);
  unsigned short* W1T = (unsigned short*)(ws + W1T_OFF);
  unsigned short* W2T = (unsigned short*)(ws + W2T_OFF);

  hipMemsetAsync(ws, 0, 256, stream);
  router_kernel<<<T_TOKENS / 4, 256, 0, stream>>>(x, router_w, router_b, tidx, tw, counts);
  scan_kernel<<<1, 64, 0, stream>>>(counts, offsets, cursors);
  gather_kernel<<<NASSIGN / 4, 256, 0, stream>>>(x, tidx, cursors, tslot, Xg);
  // W1 [E][1024][4096] -> W1T [E][4096][1024]
  transpose_cvt<<<dim3(FDIM / 64, DIM / 64, NEXP), 256, 0, stream>>>(w1, W1T, DIM, FDIM);
  // W2 [E][4096][1024] -> W2T [E][1024][4096]
  transpose_cvt<<<dim3(DIM / 64, FDIM / 64, NEXP), 256, 0, stream>>>(w2, W2T, FDIM, DIM);
  // H = gelu(Xg @ W1 + b1)
  ffn_gemm<true, DIM><<<dim3(32, FDIM / 128, NEXP), 256, 0, stream>>>(Xg, W1T, b1, H, offsets, FDIM);
  // EO = H @ W2 + b2
  ffn_gemm<false, FDIM><<<dim3(32, DIM / 128, NEXP), 256, 0, stream>>>(H, W2T, b2, EO, offsets, DIM);
  combine_kernel<<<T_TOKENS, 256, 0, stream>>>(x, EO, tslot, tw, out);
}

// Round 4
// 675.168 us; speedup vs baseline: 2.1490x; 2.1490x over previous
//
#include <hip/hip_runtime.h>

#define T_TOKENS 4096   // B*S
#define DIM      1024   // D
#define NEXP     8      // E
#define FDIM     4096   // F
#define NASSIGN  8192   // T_TOKENS * K
#define PADROWS  8448   // NASSIGN + 256 tile padding

typedef __bf16 bf16x8 __attribute__((ext_vector_type(8)));
typedef float  f32x4  __attribute__((ext_vector_type(4)));

__device__ __forceinline__ unsigned short f2b(float f) {
  unsigned u = __builtin_bit_cast(unsigned, f);
  u = u + 0x7fffu + ((u >> 16) & 1u);   // RNE, finite inputs only
  return (unsigned short)(u >> 16);
}
__device__ __forceinline__ float b2f(unsigned short h) {
  unsigned u = ((unsigned)h) << 16;
  return __builtin_bit_cast(float, u);
}
__device__ __forceinline__ void gload_lds16(const void* g, void* l) {
  __builtin_amdgcn_global_load_lds(
      (const __attribute__((address_space(1))) void*)g,
      (__attribute__((address_space(3))) void*)l, 16, 0, 0);
}

// ---------------- router: logits -> softmax -> top2 -> weights ----------------
__global__ void router_kernel(const float* __restrict__ x, const float* __restrict__ rw,
                              const float* __restrict__ rb, int* __restrict__ tidx,
                              float* __restrict__ tw, int* __restrict__ counts) {
  int gid = blockIdx.x * blockDim.x + threadIdx.x;
  int t = gid >> 6;
  int lane = threadIdx.x & 63;
  if (t >= T_TOKENS) return;
  const float* xr = x + (size_t)t * DIM;
  float acc[NEXP];
#pragma unroll
  for (int e = 0; e < NEXP; ++e) acc[e] = 0.f;
  for (int d = lane; d < DIM; d += 64) {
    float xv = xr[d];
    const float* r = rw + (size_t)d * NEXP;
#pragma unroll
    for (int e = 0; e < NEXP; ++e) acc[e] += xv * r[e];
  }
#pragma unroll
  for (int e = 0; e < NEXP; ++e) {
#pragma unroll
    for (int off = 32; off > 0; off >>= 1) acc[e] += __shfl_xor(acc[e], off);
  }
  if (lane == 0) {
    float lg[NEXP], m = -1e30f;
#pragma unroll
    for (int e = 0; e < NEXP; ++e) { lg[e] = acc[e] + rb[e]; m = fmaxf(m, lg[e]); }
    float p[NEXP], Z = 0.f;
#pragma unroll
    for (int e = 0; e < NEXP; ++e) { p[e] = expf(lg[e] - m); Z += p[e]; }
    int i0 = 0;
#pragma unroll
    for (int e = 1; e < NEXP; ++e) if (p[e] > p[i0]) i0 = e;
    int i1 = (i0 == 0) ? 1 : 0;
#pragma unroll
    for (int e = 0; e < NEXP; ++e) if (e != i0 && p[e] > p[i1]) i1 = e;
    float q0 = p[i0] / Z, q1 = p[i1] / Z;
    float s = q0 + q1 + 1e-8f;
    tidx[t * 2] = i0; tidx[t * 2 + 1] = i1;
    tw[t * 2] = q0 / s; tw[t * 2 + 1] = q1 / s;
    atomicAdd(&counts[i0], 1); atomicAdd(&counts[i1], 1);
  }
}

// ---------------- tiny scan: counts -> offsets, cursors, 256-row tile list ----------------
__global__ void scan_kernel(const int* __restrict__ counts, int* __restrict__ offsets,
                            int* __restrict__ cursors, int* __restrict__ ntiles_p,
                            int* __restrict__ tlist) {
  if (threadIdx.x == 0) {
    int s = 0;
    for (int e = 0; e < NEXP; ++e) { offsets[e] = s; cursors[e] = s; s += counts[e]; }
    offsets[NEXP] = s;
    int nt = 0;
    for (int e = 0; e < NEXP; ++e) {
      int ne = counts[e];
      int mts = (ne + 255) >> 8;
      for (int mt = 0; mt < mts; ++mt) tlist[nt++] = (e << 8) | mt;
    }
    *ntiles_p = nt;
  }
}

// ---------------- gather x rows (fp32 -> bf16) into expert-segmented Xg ----------------
__global__ void gather_kernel(const float* __restrict__ x, const int* __restrict__ tidx,
                              int* __restrict__ cursors, int* __restrict__ tslot,
                              unsigned short* __restrict__ Xg) {
  int aid = (blockIdx.x * blockDim.x + threadIdx.x) >> 6;
  int lane = threadIdx.x & 63;
  if (aid >= NASSIGN) return;
  int t = aid >> 1, k = aid & 1;
  int e = tidx[t * 2 + k];
  int slot = 0;
  if (lane == 0) {
    slot = atomicAdd(&cursors[e], 1);
    tslot[t * 2 + k] = slot;
  }
  slot = __shfl(slot, 0);
  const float4* xr = (const float4*)(x + (size_t)t * DIM);
  ushort4* dst = (ushort4*)(Xg + (size_t)slot * DIM);
#pragma unroll
  for (int i = 0; i < 4; ++i) {
    int idx = i * 64 + lane;
    float4 v = xr[idx];
    ushort4 o;
    o.x = f2b(v.x); o.y = f2b(v.y); o.z = f2b(v.z); o.w = f2b(v.w);
    dst[idx] = o;
  }
}

// ---------------- transpose + convert: src [E][R][C] f32 -> dst [E][C][R] bf16 ----------------
__global__ void transpose_cvt(const float* __restrict__ src, unsigned short* __restrict__ dst,
                              int R, int C) {
  __shared__ unsigned short tile[64][72];
  int e = blockIdx.z;
  const float* s = src + (size_t)e * R * C;
  unsigned short* d = dst + (size_t)e * R * C;
  int c0 = blockIdx.x * 64, r0 = blockIdx.y * 64;
  int tx = threadIdx.x & 15, ty = threadIdx.x >> 4;
#pragma unroll
  for (int i = 0; i < 4; ++i) {
    int r = i * 16 + ty;
    float4 v = *(const float4*)(s + (size_t)(r0 + r) * C + c0 + tx * 4);
    tile[r][tx * 4 + 0] = f2b(v.x);
    tile[r][tx * 4 + 1] = f2b(v.y);
    tile[r][tx * 4 + 2] = f2b(v.z);
    tile[r][tx * 4 + 3] = f2b(v.w);
  }
  __syncthreads();
#pragma unroll
  for (int i = 0; i < 4; ++i) {
    int c = i * 16 + ty;
    ushort4 o;
    o.x = tile[tx * 4 + 0][c];
    o.y = tile[tx * 4 + 1][c];
    o.z = tile[tx * 4 + 2][c];
    o.w = tile[tx * 4 + 3][c];
    *(ushort4*)(d + (size_t)(c0 + c) * R + r0 + tx * 4) = o;
  }
}

// ---------------- 256-wide per-expert GEMM, 2-phase dbuf, XOR-swizzled LDS ----------------
// A: [slots][K] bf16, B: [E][N][K] bf16, Out: [slots][N] bf16.
// 8 waves (2M x 4N); per-wave C = 128 x (BN/4).
// LDS swizzle: LDS[r][chunk c] = G[r][chunk c ^ (r&7)] (16B chunks); staging achieves this
// with linear gload_lds dest + pre-swizzled global source chunk ((l&7) ^ (l>>3)).
template <bool GELU, int K, int BN>
__global__ __launch_bounds__(512, 2) void ffn_gemm256(
    const unsigned short* __restrict__ A, const unsigned short* __restrict__ Bw,
    const float* __restrict__ bias, unsigned short* __restrict__ Out,
    const int* __restrict__ offsets, const int* __restrict__ ntiles_p,
    const int* __restrict__ tlist, int N) {
  constexpr int BM = 256, BK = 64;
  constexpr int NR = BN / 64;            // fragments per wave in N (4 or 2)
  constexpr int WNS = BN / 4;            // per-wave N span (64 or 32)

  // bijective XCD swizzle (nwg % 8 == 0 by grid construction)
  int gx = gridDim.x;
  int nwg = gx * gridDim.y;
  int orig = blockIdx.y * gx + blockIdx.x;
  int wgid = (orig & 7) * (nwg >> 3) + (orig >> 3);
  int xb = wgid % gx, yb = wgid / gx;

  int ntiles = *ntiles_p;
  if (yb >= ntiles) return;
  int ent = tlist[yb];
  int e = ent >> 8, mt = ent & 255;
  int off = offsets[e];
  int n_e = offsets[e + 1] - off;
  int row0 = off + mt * 256;
  int rows_valid = n_e - mt * 256; if (rows_valid > 256) rows_valid = 256;
  int n0 = xb * BN;

  __shared__ unsigned short As[2][BM * BK];
  __shared__ unsigned short Bs[2][BN * BK];

  int tid = threadIdx.x, w = tid >> 6, l = tid & 63;
  int wm = w >> 2, wn = w & 3;

  f32x4 acc[8][NR] = {};

  const unsigned short* Ab = A + (size_t)row0 * K;
  const unsigned short* Bb = Bw + ((size_t)e * N + n0) * K;
  int srow = l >> 3;                     // row within 8-row group
  int scol = ((l & 7) ^ (l >> 3)) * 8;   // pre-swizzled source col (shorts)

  auto stage = [&](int buf, int k0) {
    // each (wave, iter) stages 8 rows x BK: 64 lanes = 8 rows x 8 chunks of 16B
#pragma unroll
    for (int i = 0; i < 4; ++i) {        // A: 8 waves x 4 iters x 8 rows = 256 = BM
      int R = w * 32 + i * 8;
      gload_lds16(Ab + (size_t)(R + srow) * K + k0 + scol, &As[buf][R * BK]);
    }
#pragma unroll
    for (int i = 0; i < BN / 64; ++i) {  // B: 8 waves x (BN/64) iters x 8 rows = BN
      int R = w * (BN / 8) + i * 8;
      gload_lds16(Bb + (size_t)(R + srow) * K + k0 + scol, &Bs[buf][R * BK]);
    }
  };
  auto compute = [&](int buf) {
#pragma unroll
    for (int kk = 0; kk < 2; ++kk) {
      int cb = (kk * 64 + (l >> 4) * 16) ^ ((l & 7) << 4);   // swizzled col byte
      bf16x8 af[8], bfr[NR];
#pragma unroll
      for (int i = 0; i < 8; ++i) {
        int row = wm * 128 + i * 16 + (l & 15);
        af[i] = *(const bf16x8*)((const char*)&As[buf][0] + row * 128 + cb);
      }
#pragma unroll
      for (int j = 0; j < NR; ++j) {
        int row = wn * WNS + j * 16 + (l & 15);
        bfr[j] = *(const bf16x8*)((const char*)&Bs[buf][0] + row * 128 + cb);
      }
#pragma unroll
      for (int i = 0; i < 8; ++i)
#pragma unroll
        for (int j = 0; j < NR; ++j)
          acc[i][j] = __builtin_amdgcn_mfma_f32_16x16x32_bf16(af[i], bfr[j], acc[i][j], 0, 0, 0);
    }
  };

  stage(0, 0);
  __syncthreads();

#pragma unroll 1
  for (int k0 = 0; k0 < K; k0 += 128) {
    stage(1, k0 + 64);                   // K multiple of 128: k0+64 always < K
    compute(0);
    __syncthreads();
    if (k0 + 128 < K) stage(0, k0 + 128);
    compute(1);
    __syncthreads();
  }

  int cr = (l >> 4) * 4, cc = l & 15;
#pragma unroll
  for (int i = 0; i < 8; ++i) {
#pragma unroll
    for (int r = 0; r < 4; ++r) {
      int rl = wm * 128 + i * 16 + cr + r;
      if (rl < rows_valid) {
        size_t rowbase = (size_t)(row0 + rl) * N;
#pragma unroll
        for (int j = 0; j < NR; ++j) {
          int col = n0 + wn * WNS + j * 16 + cc;
          float v = acc[i][j][r] + bias[(size_t)e * N + col];
          if (GELU) v = 0.5f * v * (1.0f + erff(v * 0.70710678118654752f));
          Out[rowbase + col] = f2b(v);
        }
      }
    }
  }
}

// ---------------- combine: out = x + w0*EO[slot0] + w1*EO[slot1] ----------------
__global__ void combine_kernel(const float* __restrict__ x, const unsigned short* __restrict__ EO,
                               const int* __restrict__ tslot, const float* __restrict__ tw,
                               float* __restrict__ out) {
  int t = blockIdx.x;
  int s0 = tslot[t * 2], s1 = tslot[t * 2 + 1];
  float w0 = tw[t * 2], w1 = tw[t * 2 + 1];
  int i = threadIdx.x;  // float4 index, 256 * 4 = 1024 elems
  float4 xv = ((const float4*)(x + (size_t)t * DIM))[i];
  ushort4 a = ((const ushort4*)(EO + (size_t)s0 * DIM))[i];
  ushort4 b = ((const ushort4*)(EO + (size_t)s1 * DIM))[i];
  float4 o;
  o.x = xv.x + w0 * b2f(a.x) + w1 * b2f(b.x);
  o.y = xv.y + w0 * b2f(a.y) + w1 * b2f(b.y);
  o.z = xv.z + w0 * b2f(a.z) + w1 * b2f(b.z);
  o.w = xv.w + w0 * b2f(a.w) + w1 * b2f(b.w);
  ((float4*)(out + (size_t)t * DIM))[i] = o;
}

extern "C" void kernel_launch(void* const* d_in, const int* in_sizes, int n_in,
                              void* d_out, int out_size, void* d_ws, size_t ws_size,
                              hipStream_t stream) {
  const float* x        = (const float*)d_in[0];
  const float* router_w = (const float*)d_in[1];
  const float* router_b = (const float*)d_in[2];
  const float* w1       = (const float*)d_in[3];
  const float* b1       = (const float*)d_in[4];
  const float* w2       = (const float*)d_in[5];
  const float* b2       = (const float*)d_in[6];
  float* out = (float*)d_out;
  char* ws = (char*)d_ws;

  // workspace layout (bytes)
  int*   counts  = (int*)(ws + 0);
  int*   cursors = (int*)(ws + 64);
  int*   offsets = (int*)(ws + 128);
  int*   ntilesp = (int*)(ws + 192);
  int*   tlist   = (int*)(ws + 256);      // up to 40 entries
  int*   tidx    = (int*)(ws + 4096);     // 32 KB
  float* tw      = (float*)(ws + 36864);  // 32 KB
  int*   tslot   = (int*)(ws + 69632);    // 32 KB
  const size_t XG_OFF  = 1u << 20;
  const size_t XG_B    = (size_t)PADROWS * DIM * 2;
  const size_t H_OFF   = XG_OFF + XG_B;
  const size_t H_B     = (size_t)PADROWS * FDIM * 2;
  const size_t EO_OFF  = H_OFF + H_B;
  const size_t EO_B    = XG_B;
  const size_t W1T_OFF = EO_OFF + EO_B;
  const size_t WT_B    = (size_t)NEXP * DIM * FDIM * 2;
  const size_t W2T_OFF = W1T_OFF + WT_B;
  unsigned short* Xg  = (unsigned short*)(ws + XG_OFF);
  unsigned short* H   = (unsigned short*)(ws + H_OFF);
  unsigned short* EO  = (unsigned short*)(ws + EO_OFF);
  unsigned short* W1T = (unsigned short*)(ws + W1T_OFF);
  unsigned short* W2T = (unsigned short*)(ws + W2T_OFF);

  hipMemsetAsync(ws, 0, 512, stream);
  router_kernel<<<T_TOKENS / 4, 256, 0, stream>>>(x, router_w, router_b, tidx, tw, counts);
  scan_kernel<<<1, 64, 0, stream>>>(counts, offsets, cursors, ntilesp, tlist);
  gather_kernel<<<NASSIGN / 4, 256, 0, stream>>>(x, tidx, cursors, tslot, Xg);
  // W1 [E][1024][4096] -> W1T [E][4096][1024]
  transpose_cvt<<<dim3(FDIM / 64, DIM / 64, NEXP), 256, 0, stream>>>(w1, W1T, DIM, FDIM);
  // W2 [E][4096][1024] -> W2T [E][1024][4096]
  transpose_cvt<<<dim3(DIM / 64, FDIM / 64, NEXP), 256, 0, stream>>>(w2, W2T, FDIM, DIM);
  // H = gelu(Xg @ W1 + b1): grid x = n-tiles (16), y = worst-case m-tile entries (40)
  ffn_gemm256<true, DIM, 256><<<dim3(FDIM / 256, 40), 512, 0, stream>>>(
      Xg, W1T, b1, H, offsets, ntilesp, tlist, FDIM);
  // EO = H @ W2 + b2: BN=128 -> x = 8 n-tiles
  ffn_gemm256<false, FDIM, 128><<<dim3(DIM / 128, 40), 512, 0, stream>>>(
      H, W2T, b2, EO, offsets, ntilesp, tlist, DIM);
  combine_kernel<<<T_TOKENS, 256, 0, stream>>>(x, EO, tslot, tw, out);
}

// Round 5
// 603.665 us; speedup vs baseline: 2.4036x; 1.1184x over previous
//
#include <hip/hip_runtime.h>

#define T_TOKENS 4096   // B*S
#define DIM      1024   // D
#define NEXP     8      // E
#define FDIM     4096   // F
#define NASSIGN  8192   // T_TOKENS * K
#define PADROWS  8448   // NASSIGN + 256 tile padding

typedef __bf16 bf16x8 __attribute__((ext_vector_type(8)));
typedef float  f32x4  __attribute__((ext_vector_type(4)));

__device__ __forceinline__ unsigned short f2b(float f) {
  unsigned u = __builtin_bit_cast(unsigned, f);
  u = u + 0x7fffu + ((u >> 16) & 1u);   // RNE, finite inputs only
  return (unsigned short)(u >> 16);
}
__device__ __forceinline__ void gload_lds16(const void* g, void* l) {
  __builtin_amdgcn_global_load_lds(
      (const __attribute__((address_space(1))) void*)g,
      (__attribute__((address_space(3))) void*)l, 16, 0, 0);
}

#define BARR  __builtin_amdgcn_s_barrier()
#define PRIO1 __builtin_amdgcn_s_setprio(1)
#define PRIO0 __builtin_amdgcn_s_setprio(0)
#define VMC4  asm volatile("s_waitcnt vmcnt(4)" ::: "memory")

// ---------------- router: logits -> softmax -> top2 -> weights ----------------
__global__ void router_kernel(const float* __restrict__ x, const float* __restrict__ rw,
                              const float* __restrict__ rb, int* __restrict__ tidx,
                              float* __restrict__ tw, int* __restrict__ counts) {
  int gid = blockIdx.x * blockDim.x + threadIdx.x;
  int t = gid >> 6;
  int lane = threadIdx.x & 63;
  if (t >= T_TOKENS) return;
  const float* xr = x + (size_t)t * DIM;
  float acc[NEXP];
#pragma unroll
  for (int e = 0; e < NEXP; ++e) acc[e] = 0.f;
  for (int d = lane; d < DIM; d += 64) {
    float xv = xr[d];
    const float* r = rw + (size_t)d * NEXP;
#pragma unroll
    for (int e = 0; e < NEXP; ++e) acc[e] += xv * r[e];
  }
#pragma unroll
  for (int e = 0; e < NEXP; ++e) {
#pragma unroll
    for (int off = 32; off > 0; off >>= 1) acc[e] += __shfl_xor(acc[e], off);
  }
  if (lane == 0) {
    float lg[NEXP], m = -1e30f;
#pragma unroll
    for (int e = 0; e < NEXP; ++e) { lg[e] = acc[e] + rb[e]; m = fmaxf(m, lg[e]); }
    float p[NEXP], Z = 0.f;
#pragma unroll
    for (int e = 0; e < NEXP; ++e) { p[e] = expf(lg[e] - m); Z += p[e]; }
    int i0 = 0;
#pragma unroll
    for (int e = 1; e < NEXP; ++e) if (p[e] > p[i0]) i0 = e;
    int i1 = (i0 == 0) ? 1 : 0;
#pragma unroll
    for (int e = 0; e < NEXP; ++e) if (e != i0 && p[e] > p[i1]) i1 = e;
    float q0 = p[i0] / Z, q1 = p[i1] / Z;
    float s = q0 + q1 + 1e-8f;
    tidx[t * 2] = i0; tidx[t * 2 + 1] = i1;
    tw[t * 2] = q0 / s; tw[t * 2 + 1] = q1 / s;
    atomicAdd(&counts[i0], 1); atomicAdd(&counts[i1], 1);
  }
}

// ---------------- tiny scan: counts -> offsets, cursors, 256-row tile list ----------------
__global__ void scan_kernel(const int* __restrict__ counts, int* __restrict__ offsets,
                            int* __restrict__ cursors, int* __restrict__ ntiles_p,
                            int* __restrict__ tlist) {
  if (threadIdx.x == 0) {
    int s = 0;
    for (int e = 0; e < NEXP; ++e) { offsets[e] = s; cursors[e] = s; s += counts[e]; }
    offsets[NEXP] = s;
    int nt = 0;
    for (int e = 0; e < NEXP; ++e) {
      int ne = counts[e];
      int mts = (ne + 255) >> 8;
      for (int mt = 0; mt < mts; ++mt) tlist[nt++] = (e << 8) | mt;
    }
    *ntiles_p = nt;
  }
}

// ---------------- gather x rows (fp32 -> bf16) into expert-segmented Xg ----------------
__global__ void gather_kernel(const float* __restrict__ x, const int* __restrict__ tidx,
                              int* __restrict__ cursors, int* __restrict__ tslot,
                              unsigned short* __restrict__ Xg) {
  int aid = (blockIdx.x * blockDim.x + threadIdx.x) >> 6;
  int lane = threadIdx.x & 63;
  if (aid >= NASSIGN) return;
  int t = aid >> 1, k = aid & 1;
  int e = tidx[t * 2 + k];
  int slot = 0;
  if (lane == 0) {
    slot = atomicAdd(&cursors[e], 1);
    tslot[t * 2 + k] = slot;
  }
  slot = __shfl(slot, 0);
  const float4* xr = (const float4*)(x + (size_t)t * DIM);
  ushort4* dst = (ushort4*)(Xg + (size_t)slot * DIM);
#pragma unroll
  for (int i = 0; i < 4; ++i) {
    int idx = i * 64 + lane;
    float4 v = xr[idx];
    ushort4 o;
    o.x = f2b(v.x); o.y = f2b(v.y); o.z = f2b(v.z); o.w = f2b(v.w);
    dst[idx] = o;
  }
}

// ---------------- transpose + convert: src [E][R][C] f32 -> dst [E][C][R] bf16 ----------------
__global__ void transpose_cvt(const float* __restrict__ src, unsigned short* __restrict__ dst,
                              int R, int C) {
  __shared__ unsigned short tile[64][72];
  int e = blockIdx.z;
  const float* s = src + (size_t)e * R * C;
  unsigned short* d = dst + (size_t)e * R * C;
  int c0 = blockIdx.x * 64, r0 = blockIdx.y * 64;
  int tx = threadIdx.x & 15, ty = threadIdx.x >> 4;
#pragma unroll
  for (int i = 0; i < 4; ++i) {
    int r = i * 16 + ty;
    float4 v = *(const float4*)(s + (size_t)(r0 + r) * C + c0 + tx * 4);
    tile[r][tx * 4 + 0] = f2b(v.x);
    tile[r][tx * 4 + 1] = f2b(v.y);
    tile[r][tx * 4 + 2] = f2b(v.z);
    tile[r][tx * 4 + 3] = f2b(v.w);
  }
  __syncthreads();
#pragma unroll
  for (int i = 0; i < 4; ++i) {
    int c = i * 16 + ty;
    ushort4 o;
    o.x = tile[tx * 4 + 0][c];
    o.y = tile[tx * 4 + 1][c];
    o.z = tile[tx * 4 + 2][c];
    o.w = tile[tx * 4 + 3][c];
    *(ushort4*)(d + (size_t)(c0 + c) * R + r0 + tx * 4) = o;
  }
}

// ---------------- 8-phase counted-vmcnt GEMM (T3+T4+T2+T5), 256xBN tile ----------------
// A: [slots][AS] bf16, B: [E][N][AS] bf16.
// 8 waves (2M x 4N). LDS quarter-tiles staged 1 gload/thread; vmcnt(4) at ph4/ph8 only.
template <int BN, int KT, bool GELU, bool F32OUT, int AS, bool SPLITK>
__global__ __launch_bounds__(512, 2) void ffn_gemm8p(
    const unsigned short* __restrict__ A, const unsigned short* __restrict__ Bw,
    const float* __restrict__ bias, void* __restrict__ OutP,
    const int* __restrict__ offsets, const int* __restrict__ ntiles_p,
    const int* __restrict__ tlist, int N) {
  constexpr int NR  = BN / 64;   // 4 or 2
  constexpr int WNS = BN / 4;    // 64 or 32

  int gx = gridDim.x;
  int nwg = gx * gridDim.y;
  int orig = blockIdx.y * gx + blockIdx.x;
  int wgid = (orig & 7) * (nwg >> 3) + (orig >> 3);
  int xb = wgid % gx, yb = wgid / gx;
  int kh = 0;
  if (SPLITK) { kh = xb & 1; xb >>= 1; }

  int ntiles = *ntiles_p;
  if (yb >= ntiles) return;
  int ent = tlist[yb];
  int e = ent >> 8, mt = ent & 255;
  int off = offsets[e];
  int n_e = offsets[e + 1] - off;
  int row0 = off + mt * 256;
  int rows_valid = n_e - mt * 256; if (rows_valid > 256) rows_valid = 256;
  int n0 = xb * BN;
  int kbase = kh * (KT * 64);

  __shared__ unsigned short As[2][256 * 64];
  __shared__ unsigned short Bs[2][BN * 64];

  int tid = threadIdx.x, w = tid >> 6, l = tid & 63;
  int wm = w >> 2, wn = w & 3;

  f32x4 acc[8][NR] = {};

  const unsigned short* Ab = A + (size_t)row0 * AS + kbase;
  const unsigned short* Bb = Bw + ((size_t)e * N + n0) * AS + kbase;
  int srow = l >> 3;
  int scol = ((l & 7) ^ (l >> 3)) * 8;   // pre-swizzled source chunk

  auto stA = [&](int bank, int q, int lt) {
    int R = q * 64 + w * 8;
    gload_lds16(Ab + (size_t)(R + srow) * AS + lt * 64 + scol, &As[bank][R * 64]);
  };
  auto stB = [&](int bank, int q, int lt) {
    int R = q * 64 + w * 8;
    gload_lds16(Bb + (size_t)(R + srow) * AS + lt * 64 + scol, &Bs[bank][R * 64]);
  };
  const char* Ac = (const char*)&As[0][0];
  const char* Bc = (const char*)&Bs[0][0];
  auto rdA = [&](int bank, int i, int kk) {
    int row = wm * 128 + i * 16 + (l & 15);
    int cb = (kk * 64 + (l >> 4) * 16) ^ ((l & 7) << 4);
    return *(const bf16x8*)(Ac + bank * (256 * 128) + row * 128 + cb);
  };
  auto rdB = [&](int bank, int j, int kk) {
    int row = wn * WNS + j * 16 + (l & 15);
    int cb = (kk * 64 + (l >> 4) * 16) ^ ((l & 7) << 4);
    return *(const bf16x8*)(Bc + bank * (BN * 128) + row * 128 + cb);
  };
  auto MM = [&](bf16x8 a, bf16x8 b, f32x4& c) {
    c = __builtin_amdgcn_mfma_f32_16x16x32_bf16(a, b, c, 0, 0, 0);
  };

  // ---- prologue: tile0 full, tile1 first half; vmcnt(4) -> tile0 landed
  stA(0, 0, 0); stA(0, 1, 0); stA(0, 2, 0); stA(0, 3, 0);
  stB(0, 0, 0); stB(0, 1, 0);
  if (NR == 4) { stB(0, 2, 0); stB(0, 3, 0); }
  stA(1, 0, 1); stA(1, 2, 1);
  stB(1, 0, 1); stB(1, 1, 1);
  VMC4;
  BARR;

#pragma unroll 1
  for (int it = 0; it < KT / 2; ++it) {
    int t = 2 * it;
    int lt1 = t + 1, lt2 = (t + 2) & (KT - 1), lt3 = (t + 3) & (KT - 1);
    bf16x8 afL[4][2], afH[4][2], bf01[2][2], bf23[2][2];

    // ---- ph1: read afL + bf01 (bank0); stage t1 remainder part A/B
#pragma unroll
    for (int i = 0; i < 4; ++i) { afL[i][0] = rdA(0, i, 0); afL[i][1] = rdA(0, i, 1); }
#pragma unroll
    for (int j = 0; j < 2; ++j) { bf01[j][0] = rdB(0, j, 0); bf01[j][1] = rdB(0, j, 1); }
    if (NR == 4) { stB(1, 2, lt1); stB(1, 3, lt1); }
    else         { stA(1, 1, lt1); stA(1, 3, lt1); }
    BARR; PRIO1;
#pragma unroll
    for (int i = 0; i < 4; ++i)
#pragma unroll
      for (int j = 0; j < 2; ++j) {
        MM(afL[i][0], bf01[j][0], acc[i][j]);
        if (NR == 4) MM(afL[i][1], bf01[j][1], acc[i][j]);
      }
    PRIO0; BARR;

    // ---- ph2
    if (NR == 4) {
#pragma unroll
      for (int j = 0; j < 2; ++j) { bf23[j][0] = rdB(0, 2 + j, 0); bf23[j][1] = rdB(0, 2 + j, 1); }
      stA(1, 1, lt1); stA(1, 3, lt1);
    }
    BARR; PRIO1;
#pragma unroll
    for (int i = 0; i < 4; ++i)
#pragma unroll
      for (int j = 0; j < 2; ++j) {
        if (NR == 4) { MM(afL[i][0], bf23[j][0], acc[i][2 + j]); MM(afL[i][1], bf23[j][1], acc[i][2 + j]); }
        else         { MM(afL[i][1], bf01[j][1], acc[i][j]); }
      }
    PRIO0; BARR;

    // ---- ph3: read afH (bank0); stage t2 A-Q0,Q2
#pragma unroll
    for (int i = 0; i < 4; ++i) { afH[i][0] = rdA(0, 4 + i, 0); afH[i][1] = rdA(0, 4 + i, 1); }
    stA(0, 0, lt2); stA(0, 2, lt2);
    BARR; PRIO1;
#pragma unroll
    for (int i = 0; i < 4; ++i)
#pragma unroll
      for (int j = 0; j < 2; ++j) {
        MM(afH[i][0], bf01[j][0], acc[4 + i][j]);
        if (NR == 4) MM(afH[i][1], bf01[j][1], acc[4 + i][j]);
      }
    PRIO0; BARR;

    // ---- ph4: stage t2 B-Q0,Q1; vmcnt(4)
    stB(0, 0, lt2); stB(0, 1, lt2);
    BARR; PRIO1;
#pragma unroll
    for (int i = 0; i < 4; ++i)
#pragma unroll
      for (int j = 0; j < 2; ++j) {
        if (NR == 4) { MM(afH[i][0], bf23[j][0], acc[4 + i][2 + j]); MM(afH[i][1], bf23[j][1], acc[4 + i][2 + j]); }
        else         { MM(afH[i][1], bf01[j][1], acc[4 + i][j]); }
      }
    PRIO0; VMC4; BARR;

    // ---- ph5: read afL + bf01 (bank1); stage t2 remainder
#pragma unroll
    for (int i = 0; i < 4; ++i) { afL[i][0] = rdA(1, i, 0); afL[i][1] = rdA(1, i, 1); }
#pragma unroll
    for (int j = 0; j < 2; ++j) { bf01[j][0] = rdB(1, j, 0); bf01[j][1] = rdB(1, j, 1); }
    stA(0, 1, lt2); stA(0, 3, lt2);
    if (NR == 4) { stB(0, 2, lt2); stB(0, 3, lt2); }
    BARR; PRIO1;
#pragma unroll
    for (int i = 0; i < 4; ++i)
#pragma unroll
      for (int j = 0; j < 2; ++j) {
        MM(afL[i][0], bf01[j][0], acc[i][j]);
        if (NR == 4) MM(afL[i][1], bf01[j][1], acc[i][j]);
      }
    PRIO0; BARR;

    // ---- ph6
    if (NR == 4) {
#pragma unroll
      for (int j = 0; j < 2; ++j) { bf23[j][0] = rdB(1, 2 + j, 0); bf23[j][1] = rdB(1, 2 + j, 1); }
    }
    BARR; PRIO1;
#pragma unroll
    for (int i = 0; i < 4; ++i)
#pragma unroll
      for (int j = 0; j < 2; ++j) {
        if (NR == 4) { MM(afL[i][0], bf23[j][0], acc[i][2 + j]); MM(afL[i][1], bf23[j][1], acc[i][2 + j]); }
        else         { MM(afL[i][1], bf01[j][1], acc[i][j]); }
      }
    PRIO0; BARR;

    // ---- ph7: read afH (bank1); stage t3 A-Q0,Q2
#pragma unroll
    for (int i = 0; i < 4; ++i) { afH[i][0] = rdA(1, 4 + i, 0); afH[i][1] = rdA(1, 4 + i, 1); }
    stA(1, 0, lt3); stA(1, 2, lt3);
    BARR; PRIO1;
#pragma unroll
    for (int i = 0; i < 4; ++i)
#pragma unroll
      for (int j = 0; j < 2; ++j) {
        MM(afH[i][0], bf01[j][0], acc[4 + i][j]);
        if (NR == 4) MM(afH[i][1], bf01[j][1], acc[4 + i][j]);
      }
    PRIO0; BARR;

    // ---- ph8: stage t3 B-Q0,Q1; vmcnt(4)
    stB(1, 0, lt3); stB(1, 1, lt3);
    BARR; PRIO1;
#pragma unroll
    for (int i = 0; i < 4; ++i)
#pragma unroll
      for (int j = 0; j < 2; ++j) {
        if (NR == 4) { MM(afH[i][0], bf23[j][0], acc[4 + i][2 + j]); MM(afH[i][1], bf23[j][1], acc[4 + i][2 + j]); }
        else         { MM(afH[i][1], bf01[j][1], acc[4 + i][j]); }
      }
    PRIO0; VMC4; BARR;
  }

  // ---- epilogue / C-write
  int cr = (l >> 4) * 4, cc = l & 15;
#pragma unroll
  for (int i = 0; i < 8; ++i) {
#pragma unroll
    for (int r = 0; r < 4; ++r) {
      int rl = wm * 128 + i * 16 + cr + r;
      if (rl < rows_valid) {
#pragma unroll
        for (int j = 0; j < NR; ++j) {
          int col = n0 + wn * WNS + j * 16 + cc;
          if (F32OUT) {
            float* Of = (float*)OutP;
            Of[((size_t)(kh * PADROWS) + row0 + rl) * DIM + col] = acc[i][j][r];
          } else {
            unsigned short* Oh = (unsigned short*)OutP;
            float v = acc[i][j][r] + bias[(size_t)e * N + col];
            if (GELU) v = 0.5f * v * (1.0f + erff(v * 0.70710678118654752f));
            Oh[(size_t)(row0 + rl) * N + col] = f2b(v);
          }
        }
      }
    }
  }
}

// ---------------- combine: out = x + sum_k w_k*(EOp0[s_k]+EOp1[s_k]+b2[e_k]) ----------------
__global__ void combine_kernel(const float* __restrict__ x, const float* __restrict__ EOp,
                               const int* __restrict__ tslot, const int* __restrict__ tidx,
                               const float* __restrict__ tw, const float* __restrict__ b2,
                               float* __restrict__ out) {
  int t = blockIdx.x;
  int s0 = tslot[t * 2], s1 = tslot[t * 2 + 1];
  int e0 = tidx[t * 2], e1 = tidx[t * 2 + 1];
  float w0 = tw[t * 2], w1 = tw[t * 2 + 1];
  int i = threadIdx.x;  // float4 index
  const float4* E4 = (const float4*)EOp;
  float4 xv = ((const float4*)(x + (size_t)t * DIM))[i];
  float4 a0 = E4[((size_t)s0) * 256 + i];
  float4 a1 = E4[((size_t)PADROWS + s0) * 256 + i];
  float4 c0 = E4[((size_t)s1) * 256 + i];
  float4 c1 = E4[((size_t)PADROWS + s1) * 256 + i];
  float4 b0 = ((const float4*)(b2 + (size_t)e0 * DIM))[i];
  float4 b1 = ((const float4*)(b2 + (size_t)e1 * DIM))[i];
  float4 o;
  o.x = xv.x + w0 * (a0.x + a1.x + b0.x) + w1 * (c0.x + c1.x + b1.x);
  o.y = xv.y + w0 * (a0.y + a1.y + b0.y) + w1 * (c0.y + c1.y + b1.y);
  o.z = xv.z + w0 * (a0.z + a1.z + b0.z) + w1 * (c0.z + c1.z + b1.z);
  o.w = xv.w + w0 * (a0.w + a1.w + b0.w) + w1 * (c0.w + c1.w + b1.w);
  ((float4*)(out + (size_t)t * DIM))[i] = o;
}

extern "C" void kernel_launch(void* const* d_in, const int* in_sizes, int n_in,
                              void* d_out, int out_size, void* d_ws, size_t ws_size,
                              hipStream_t stream) {
  const float* x        = (const float*)d_in[0];
  const float* router_w = (const float*)d_in[1];
  const float* router_b = (const float*)d_in[2];
  const float* w1       = (const float*)d_in[3];
  const float* b1       = (const float*)d_in[4];
  const float* w2       = (const float*)d_in[5];
  const float* b2       = (const float*)d_in[6];
  float* out = (float*)d_out;
  char* ws = (char*)d_ws;

  // metadata
  int*   counts  = (int*)(ws + 0);
  int*   cursors = (int*)(ws + 64);
  int*   offsets = (int*)(ws + 128);
  int*   ntilesp = (int*)(ws + 192);
  int*   tlist   = (int*)(ws + 256);
  int*   tidx    = (int*)(ws + 4096);
  float* tw      = (float*)(ws + 36864);
  int*   tslot   = (int*)(ws + 69632);
  // big buffers: [Xg][H][W2T][W1T | EOp(aliases W1T, GEMM1 done before GEMM2 writes)]
  const size_t XG_OFF  = 1u << 20;
  const size_t XG_B    = (size_t)PADROWS * DIM * 2;        // 17.3 MB
  const size_t H_OFF   = XG_OFF + XG_B;
  const size_t H_B     = (size_t)PADROWS * FDIM * 2;       // 69.2 MB
  const size_t W2T_OFF = H_OFF + H_B;
  const size_t WT_B    = (size_t)NEXP * DIM * FDIM * 2;    // 67.1 MB
  const size_t W1T_OFF = W2T_OFF + WT_B;
  const size_t EOP_OFF = W1T_OFF;                          // alias
  unsigned short* Xg  = (unsigned short*)(ws + XG_OFF);
  unsigned short* H   = (unsigned short*)(ws + H_OFF);
  unsigned short* W2T = (unsigned short*)(ws + W2T_OFF);
  unsigned short* W1T = (unsigned short*)(ws + W1T_OFF);
  float*          EOp = (float*)(ws + EOP_OFF);            // [2][PADROWS][DIM] f32

  hipMemsetAsync(ws, 0, 512, stream);
  router_kernel<<<T_TOKENS / 4, 256, 0, stream>>>(x, router_w, router_b, tidx, tw, counts);
  scan_kernel<<<1, 64, 0, stream>>>(counts, offsets, cursors, ntilesp, tlist);
  gather_kernel<<<NASSIGN / 4, 256, 0, stream>>>(x, tidx, cursors, tslot, Xg);
  // W1 [E][1024][4096] -> W1T [E][4096][1024]
  transpose_cvt<<<dim3(FDIM / 64, DIM / 64, NEXP), 256, 0, stream>>>(w1, W1T, DIM, FDIM);
  // W2 [E][4096][1024] -> W2T [E][1024][4096]
  transpose_cvt<<<dim3(DIM / 64, FDIM / 64, NEXP), 256, 0, stream>>>(w2, W2T, FDIM, DIM);
  // H = gelu(Xg @ W1 + b1): BN=256, KT=16
  ffn_gemm8p<256, 16, true, false, DIM, false><<<dim3(16, 40), 512, 0, stream>>>(
      Xg, W1T, b1, (void*)H, offsets, ntilesp, tlist, FDIM);
  // EOp[kh] = H @ W2 (partial K halves, f32, bias deferred): BN=128, KT=32, split-K=2
  ffn_gemm8p<128, 32, false, true, FDIM, true><<<dim3(16, 40), 512, 0, stream>>>(
      H, W2T, b2, (void*)EOp, offsets, ntilesp, tlist, DIM);
  combine_kernel<<<T_TOKENS, 256, 0, stream>>>(x, EOp, tslot, tidx, tw, b2, out);
}

// Round 6
// 532.306 us; speedup vs baseline: 2.7258x; 1.1341x over previous
//
#include <hip/hip_runtime.h>

#define T_TOKENS 4096   // B*S
#define DIM      1024   // D
#define NEXP     8      // E
#define FDIM     4096   // F
#define NASSIGN  8192   // T_TOKENS * K
#define PADROWS  8448

typedef __bf16 bf16x8 __attribute__((ext_vector_type(8)));
typedef float  f32x4  __attribute__((ext_vector_type(4)));

__device__ __forceinline__ unsigned short f2b(float f) {
  unsigned u = __builtin_bit_cast(unsigned, f);
  u = u + 0x7fffu + ((u >> 16) & 1u);   // RNE, finite inputs only
  return (unsigned short)(u >> 16);
}
__device__ __forceinline__ void gload_lds16(const void* g, void* l) {
  __builtin_amdgcn_global_load_lds(
      (const __attribute__((address_space(1))) void*)g,
      (__attribute__((address_space(3))) void*)l, 16, 0, 0);
}

// ---------------- router: logits -> softmax -> top2 -> weights ----------------
__global__ void router_kernel(const float* __restrict__ x, const float* __restrict__ rw,
                              const float* __restrict__ rb, int* __restrict__ tidx,
                              float* __restrict__ tw, int* __restrict__ counts) {
  int gid = blockIdx.x * blockDim.x + threadIdx.x;
  int t = gid >> 6;
  int lane = threadIdx.x & 63;
  if (t >= T_TOKENS) return;
  const float* xr = x + (size_t)t * DIM;
  float acc[NEXP];
#pragma unroll
  for (int e = 0; e < NEXP; ++e) acc[e] = 0.f;
  for (int d = lane; d < DIM; d += 64) {
    float xv = xr[d];
    const float* r = rw + (size_t)d * NEXP;
#pragma unroll
    for (int e = 0; e < NEXP; ++e) acc[e] += xv * r[e];
  }
#pragma unroll
  for (int e = 0; e < NEXP; ++e) {
#pragma unroll
    for (int off = 32; off > 0; off >>= 1) acc[e] += __shfl_xor(acc[e], off);
  }
  if (lane == 0) {
    float lg[NEXP], m = -1e30f;
#pragma unroll
    for (int e = 0; e < NEXP; ++e) { lg[e] = acc[e] + rb[e]; m = fmaxf(m, lg[e]); }
    float p[NEXP], Z = 0.f;
#pragma unroll
    for (int e = 0; e < NEXP; ++e) { p[e] = expf(lg[e] - m); Z += p[e]; }
    int i0 = 0;
#pragma unroll
    for (int e = 1; e < NEXP; ++e) if (p[e] > p[i0]) i0 = e;
    int i1 = (i0 == 0) ? 1 : 0;
#pragma unroll
    for (int e = 0; e < NEXP; ++e) if (e != i0 && p[e] > p[i1]) i1 = e;
    float q0 = p[i0] / Z, q1 = p[i1] / Z;
    float s = q0 + q1 + 1e-8f;
    tidx[t * 2] = i0; tidx[t * 2 + 1] = i1;
    tw[t * 2] = q0 / s; tw[t * 2 + 1] = q1 / s;
    atomicAdd(&counts[i0], 1); atomicAdd(&counts[i1], 1);
  }
}

// ---------------- tiny scan: counts -> offsets, cursors, 128-row tile list ----------------
__global__ void scan_kernel(const int* __restrict__ counts, int* __restrict__ offsets,
                            int* __restrict__ cursors, int* __restrict__ ntiles_p,
                            int* __restrict__ tlist) {
  if (threadIdx.x == 0) {
    int s = 0;
    for (int e = 0; e < NEXP; ++e) { offsets[e] = s; cursors[e] = s; s += counts[e]; }
    offsets[NEXP] = s;
    int nt = 0;
    for (int e = 0; e < NEXP; ++e) {
      int ne = counts[e];
      int mts = (ne + 127) >> 7;
      for (int mt = 0; mt < mts; ++mt) tlist[nt++] = (e << 8) | mt;
    }
    *ntiles_p = nt;   // <= 71
  }
}

// ---------------- gather x rows (fp32 -> bf16) into expert-segmented Xg ----------------
__global__ void gather_kernel(const float* __restrict__ x, const int* __restrict__ tidx,
                              int* __restrict__ cursors, int* __restrict__ tslot,
                              unsigned short* __restrict__ Xg) {
  int aid = (blockIdx.x * blockDim.x + threadIdx.x) >> 6;
  int lane = threadIdx.x & 63;
  if (aid >= NASSIGN) return;
  int t = aid >> 1, k = aid & 1;
  int e = tidx[t * 2 + k];
  int slot = 0;
  if (lane == 0) {
    slot = atomicAdd(&cursors[e], 1);
    tslot[t * 2 + k] = slot;
  }
  slot = __shfl(slot, 0);
  const float4* xr = (const float4*)(x + (size_t)t * DIM);
  ushort4* dst = (ushort4*)(Xg + (size_t)slot * DIM);
#pragma unroll
  for (int i = 0; i < 4; ++i) {
    int idx = i * 64 + lane;
    float4 v = xr[idx];
    ushort4 o;
    o.x = f2b(v.x); o.y = f2b(v.y); o.z = f2b(v.z); o.w = f2b(v.w);
    dst[idx] = o;
  }
}

// ---------------- transpose + convert: src [E][R][C] f32 -> dst [E][C][R] bf16 ----------------
__global__ void transpose_cvt(const float* __restrict__ src, unsigned short* __restrict__ dst,
                              int R, int C) {
  __shared__ unsigned short tile[64][72];
  int e = blockIdx.z;
  const float* s = src + (size_t)e * R * C;
  unsigned short* d = dst + (size_t)e * R * C;
  int c0 = blockIdx.x * 64, r0 = blockIdx.y * 64;
  int tx = threadIdx.x & 15, ty = threadIdx.x >> 4;
#pragma unroll
  for (int i = 0; i < 4; ++i) {
    int r = i * 16 + ty;
    float4 v = *(const float4*)(s + (size_t)(r0 + r) * C + c0 + tx * 4);
    tile[r][tx * 4 + 0] = f2b(v.x);
    tile[r][tx * 4 + 1] = f2b(v.y);
    tile[r][tx * 4 + 2] = f2b(v.z);
    tile[r][tx * 4 + 3] = f2b(v.w);
  }
  __syncthreads();
#pragma unroll
  for (int i = 0; i < 4; ++i) {
    int c = i * 16 + ty;
    ushort4 o;
    o.x = tile[tx * 4 + 0][c];
    o.y = tile[tx * 4 + 1][c];
    o.z = tile[tx * 4 + 2][c];
    o.w = tile[tx * 4 + 3][c];
    *(ushort4*)(d + (size_t)(c0 + c) * R + r0 + tx * 4) = o;
  }
}

// ---------------- m97-structure 128x128 GEMM: 4 waves, 32KB LDS, TLP-hiding ----------------
// A: [slots][AS] bf16, B: [E][N][AS] bf16. 4 waves (2M x 2N), per-wave C = 64x64.
// LDS swizzle (R4-proven): LDS[r][chunk c] = G[r][c ^ (r&7)], staged via pre-swizzled
// global source chunk; fragment reads XOR chunk with row&7. Zero bank conflicts.
template <bool GELU, int AS, bool F32OUT, bool SPLITK, int SPAN>
__global__ __launch_bounds__(256, 4) void ffn_gemm128(
    const unsigned short* __restrict__ A, const unsigned short* __restrict__ Bw,
    const float* __restrict__ bias, void* __restrict__ OutP,
    const int* __restrict__ offsets, const int* __restrict__ ntiles_p,
    const int* __restrict__ tlist, int N) {
  // bijective XCD swizzle (nwg % 8 == 0 by grid construction)
  int gx = gridDim.x;
  int nwg = gx * gridDim.y;
  int orig = blockIdx.y * gx + blockIdx.x;
  int wgid = (orig & 7) * (nwg >> 3) + (orig >> 3);
  int xb = wgid % gx, yb = wgid / gx;
  int kh = 0;
  if (SPLITK) { kh = xb & 1; xb >>= 1; }

  int ntiles = *ntiles_p;
  if (yb >= ntiles) return;
  int ent = tlist[yb];
  int e = ent >> 8, mt = ent & 255;
  int off = offsets[e];
  int n_e = offsets[e + 1] - off;
  int row0 = off + mt * 128;
  if (mt * 128 >= n_e) return;
  int rows_valid = n_e - mt * 128; if (rows_valid > 128) rows_valid = 128;
  int n0 = xb * 128;
  int kbase = kh * SPAN;

  __shared__ unsigned short As[128 * 64];
  __shared__ unsigned short Bs[128 * 64];

  int tid = threadIdx.x, w = tid >> 6, l = tid & 63;
  int wm = w >> 1, wn = w & 1;

  f32x4 acc[4][4] = {};

  const unsigned short* Ab = A + (size_t)row0 * AS;
  const unsigned short* Bb = Bw + ((size_t)e * N + n0) * AS;
  int srow = l >> 3;                     // row within 8-row group
  int scol = ((l & 7) ^ (l >> 3)) * 8;   // pre-swizzled source chunk (shorts)

#pragma unroll 1
  for (int k0 = kbase; k0 < kbase + SPAN; k0 += 64) {
    // stage: 4 waves x 4 iters x 8 rows = 128 rows each for A and B
#pragma unroll
    for (int i = 0; i < 4; ++i) {
      int R = w * 32 + i * 8;
      gload_lds16(Ab + (size_t)(R + srow) * AS + k0 + scol, &As[R * 64]);
      gload_lds16(Bb + (size_t)(R + srow) * AS + k0 + scol, &Bs[R * 64]);
    }
    __syncthreads();   // compiler drains vmcnt(0); other resident blocks hide it
#pragma unroll
    for (int kk = 0; kk < 2; ++kk) {
      int cb = (kk * 64 + (l >> 4) * 16) ^ ((l & 7) << 4);   // swizzled col byte
      bf16x8 af[4], bfr[4];
#pragma unroll
      for (int i = 0; i < 4; ++i) {
        int row = wm * 64 + i * 16 + (l & 15);
        af[i] = *(const bf16x8*)((const char*)&As[0] + row * 128 + cb);
      }
#pragma unroll
      for (int j = 0; j < 4; ++j) {
        int row = wn * 64 + j * 16 + (l & 15);
        bfr[j] = *(const bf16x8*)((const char*)&Bs[0] + row * 128 + cb);
      }
#pragma unroll
      for (int i = 0; i < 4; ++i)
#pragma unroll
        for (int j = 0; j < 4; ++j)
          acc[i][j] = __builtin_amdgcn_mfma_f32_16x16x32_bf16(af[i], bfr[j], acc[i][j], 0, 0, 0);
    }
    __syncthreads();
  }

  int cr = (l >> 4) * 4, cc = l & 15;
#pragma unroll
  for (int i = 0; i < 4; ++i) {
#pragma unroll
    for (int r = 0; r < 4; ++r) {
      int rl = wm * 64 + i * 16 + cr + r;
      if (rl < rows_valid) {
#pragma unroll
        for (int j = 0; j < 4; ++j) {
          int col = n0 + wn * 64 + j * 16 + cc;
          if (F32OUT) {
            float* Of = (float*)OutP;
            Of[((size_t)(kh * PADROWS) + row0 + rl) * DIM + col] = acc[i][j][r];
          } else {
            unsigned short* Oh = (unsigned short*)OutP;
            float v = acc[i][j][r] + bias[(size_t)e * N + col];
            if (GELU) v = 0.5f * v * (1.0f + erff(v * 0.70710678118654752f));
            Oh[(size_t)(row0 + rl) * N + col] = f2b(v);
          }
        }
      }
    }
  }
}

// ---------------- combine: out = x + sum_k w_k*(EOp0[s_k]+EOp1[s_k]+b2[e_k]) ----------------
__global__ void combine_kernel(const float* __restrict__ x, const float* __restrict__ EOp,
                               const int* __restrict__ tslot, const int* __restrict__ tidx,
                               const float* __restrict__ tw, const float* __restrict__ b2,
                               float* __restrict__ out) {
  int t = blockIdx.x;
  int s0 = tslot[t * 2], s1 = tslot[t * 2 + 1];
  int e0 = tidx[t * 2], e1 = tidx[t * 2 + 1];
  float w0 = tw[t * 2], w1 = tw[t * 2 + 1];
  int i = threadIdx.x;
  const float4* E4 = (const float4*)EOp;
  float4 xv = ((const float4*)(x + (size_t)t * DIM))[i];
  float4 a0 = E4[((size_t)s0) * 256 + i];
  float4 a1 = E4[((size_t)PADROWS + s0) * 256 + i];
  float4 c0 = E4[((size_t)s1) * 256 + i];
  float4 c1 = E4[((size_t)PADROWS + s1) * 256 + i];
  float4 b0 = ((const float4*)(b2 + (size_t)e0 * DIM))[i];
  float4 b1 = ((const float4*)(b2 + (size_t)e1 * DIM))[i];
  float4 o;
  o.x = xv.x + w0 * (a0.x + a1.x + b0.x) + w1 * (c0.x + c1.x + b1.x);
  o.y = xv.y + w0 * (a0.y + a1.y + b0.y) + w1 * (c0.y + c1.y + b1.y);
  o.z = xv.z + w0 * (a0.z + a1.z + b0.z) + w1 * (c0.z + c1.z + b1.z);
  o.w = xv.w + w0 * (a0.w + a1.w + b0.w) + w1 * (c0.w + c1.w + b1.w);
  ((float4*)(out + (size_t)t * DIM))[i] = o;
}

extern "C" void kernel_launch(void* const* d_in, const int* in_sizes, int n_in,
                              void* d_out, int out_size, void* d_ws, size_t ws_size,
                              hipStream_t stream) {
  const float* x        = (const float*)d_in[0];
  const float* router_w = (const float*)d_in[1];
  const float* router_b = (const float*)d_in[2];
  const float* w1       = (const float*)d_in[3];
  const float* b1       = (const float*)d_in[4];
  const float* w2       = (const float*)d_in[5];
  const float* b2       = (const float*)d_in[6];
  float* out = (float*)d_out;
  char* ws = (char*)d_ws;

  int*   counts  = (int*)(ws + 0);
  int*   cursors = (int*)(ws + 64);
  int*   offsets = (int*)(ws + 128);
  int*   ntilesp = (int*)(ws + 192);
  int*   tlist   = (int*)(ws + 256);      // up to 71 entries
  int*   tidx    = (int*)(ws + 4096);
  float* tw      = (float*)(ws + 36864);
  int*   tslot   = (int*)(ws + 69632);
  const size_t XG_OFF  = 1u << 20;
  const size_t XG_B    = (size_t)PADROWS * DIM * 2;
  const size_t H_OFF   = XG_OFF + XG_B;
  const size_t H_B     = (size_t)PADROWS * FDIM * 2;
  const size_t W2T_OFF = H_OFF + H_B;
  const size_t WT_B    = (size_t)NEXP * DIM * FDIM * 2;
  const size_t W1T_OFF = W2T_OFF + WT_B;
  const size_t EOP_OFF = W1T_OFF;                          // alias (W1T dead after GEMM1)
  unsigned short* Xg  = (unsigned short*)(ws + XG_OFF);
  unsigned short* H   = (unsigned short*)(ws + H_OFF);
  unsigned short* W2T = (unsigned short*)(ws + W2T_OFF);
  unsigned short* W1T = (unsigned short*)(ws + W1T_OFF);
  float*          EOp = (float*)(ws + EOP_OFF);            // [2][PADROWS][DIM] f32

  hipMemsetAsync(ws, 0, 512, stream);
  router_kernel<<<T_TOKENS / 4, 256, 0, stream>>>(x, router_w, router_b, tidx, tw, counts);
  scan_kernel<<<1, 64, 0, stream>>>(counts, offsets, cursors, ntilesp, tlist);
  gather_kernel<<<NASSIGN / 4, 256, 0, stream>>>(x, tidx, cursors, tslot, Xg);
  transpose_cvt<<<dim3(FDIM / 64, DIM / 64, NEXP), 256, 0, stream>>>(w1, W1T, DIM, FDIM);
  transpose_cvt<<<dim3(DIM / 64, FDIM / 64, NEXP), 256, 0, stream>>>(w2, W2T, FDIM, DIM);
  // H = gelu(Xg @ W1 + b1): x = 32 n-tiles, y = 72 (worst-case 128-row m-tiles)
  ffn_gemm128<true, DIM, false, false, DIM><<<dim3(FDIM / 128, 72), 256, 0, stream>>>(
      Xg, W1T, b1, (void*)H, offsets, ntilesp, tlist, FDIM);
  // EOp[kh] = H @ W2 (K split in halves, f32 partials, bias deferred): x = 8 n-tiles x 2 kh
  ffn_gemm128<false, FDIM, true, true, FDIM / 2><<<dim3(DIM / 128 * 2, 72), 256, 0, stream>>>(
      H, W2T, b2, (void*)EOp, offsets, ntilesp, tlist, DIM);
  combine_kernel<<<T_TOKENS, 256, 0, stream>>>(x, EOp, tslot, tidx, tw, b2, out);
}